// Round 7
// baseline (184.375 us; speedup 1.0000x reference)
//
#include <hip/hip_runtime.h>
#include <math.h>

// VectorQuantizer via bf16-split MFMA + exact-fp32 fallback.
// v7: codebook split hoisted to prep kernel (global, B-frag layout);
//     main kernel = 256 thr / 64 rows / ~4KB LDS; wave-pairs split the
//     codebook (k-halves) and merge via LDS -> 4096 waves, 3-4x occupancy.
// inputs: x [65536,64] f32, cb [64,512] f32.
// out (flat f32): ste[4194304] | perplexity | codebook_loss | commitment_loss
// ws: counts u32[512] @0 | lossSum f32 @2048 | Cn f32[512] @4096 |
//     gB bf16-split sections @8192 (128KB) | cbTg f32[512][64] @139264 (128KB)

#define NUM_K  512
#define DIM    64
#define NROWS  65536
#define NELEM  (NROWS * DIM)
#define EPS    1e-3f

typedef __attribute__((ext_vector_type(8)))  short  short8;   // 8 bf16 (4 VGPR)
typedef __attribute__((ext_vector_type(16))) float  f32x16;   // MFMA acc
typedef __attribute__((ext_vector_type(4)))  unsigned int   uint4v;

static __device__ __forceinline__ unsigned short f2bf(float f) {
    unsigned u = __float_as_uint(f);
    u += 0x7fffu + ((u >> 16) & 1u);          // RNE
    return (unsigned short)(u >> 16);
}
static __device__ __forceinline__ float bf2f(unsigned short h) {
    return __uint_as_float(((unsigned)h) << 16);
}

// ---------------- prep: split codebook -> global gB (B-frag sections),
// Cn, transposed cbTg. Section addressing identical to verified round-4 Ebuf:
// h: sec g=(d>>3) at gB+g*8192+k*16 ; l: sec 8+g. (16 sections * 8192 B)
__global__ __launch_bounds__(128) void vq_prep(const float* __restrict__ cb,
                                               float* __restrict__ Cn,
                                               char* __restrict__ gB,
                                               float* __restrict__ cbTg)
{
    const int k = blockIdx.x * 128 + threadIdx.x;   // 0..511
    float a = 0.0f;
    #pragma unroll
    for (int g = 0; g < 8; ++g) {
        uint4v hh, ll;
        unsigned hw[4], lw[4];
        #pragma unroll
        for (int m = 0; m < 4; ++m) {
            int d0 = g * 8 + 2 * m;
            float va = cb[(size_t)d0 * NUM_K + k];
            float vb = cb[(size_t)(d0 + 1) * NUM_K + k];
            a = fmaf(va, va, a);                    // ascending-d chain (verified)
            a = fmaf(vb, vb, a);
            unsigned short ha = f2bf(va), hb = f2bf(vb);
            unsigned short la = f2bf(va - bf2f(ha)), lb = f2bf(vb - bf2f(hb));
            hw[m] = (unsigned)ha | ((unsigned)hb << 16);
            lw[m] = (unsigned)la | ((unsigned)lb << 16);
            cbTg[(size_t)k * DIM + d0]     = va;
            cbTg[(size_t)k * DIM + d0 + 1] = vb;
        }
        hh.x = hw[0]; hh.y = hw[1]; hh.z = hw[2]; hh.w = hw[3];
        ll.x = lw[0]; ll.y = lw[1]; ll.z = lw[2]; ll.w = lw[3];
        *(uint4v*)(gB + (size_t)g * 8192 + k * 16)       = hh;
        *(uint4v*)(gB + (size_t)(8 + g) * 8192 + k * 16) = ll;
    }
    Cn[k] = a;
}

// exact fallback: half-wave (32 lanes) full rescan of one row.
// Bit-identical to the round-2/4/6 verified computation.
static __device__ __forceinline__ int halfScan(const float* __restrict__ x,
                                               const float* __restrict__ cb,
                                               const float* __restrict__ CnL,
                                               int row, int j)
{
    float v0 = x[(size_t)row * DIM + j];
    float v1 = x[(size_t)row * DIM + 32 + j];
    float p0 = v0 * v0, p1 = v1 * v1;
    #pragma unroll
    for (int s = 1; s < 32; s <<= 1) { p0 += __shfl_xor(p0, s, 64); p1 += __shfl_xor(p1, s, 64); }
    float A = p0 + p1;

    float sacc[16];
    #pragma unroll
    for (int c = 0; c < 16; ++c) sacc[c] = 0.0f;
    #pragma unroll 4
    for (int d = 0; d < DIM; ++d) {
        float xv = x[(size_t)row * DIM + d];
        const float* eb = cb + (size_t)d * NUM_K + j * 16;
        float4 e0 = *(const float4*)(eb);
        float4 e1 = *(const float4*)(eb + 4);
        float4 e2 = *(const float4*)(eb + 8);
        float4 e3 = *(const float4*)(eb + 12);
        sacc[0]  = fmaf(xv, e0.x, sacc[0]);  sacc[1]  = fmaf(xv, e0.y, sacc[1]);
        sacc[2]  = fmaf(xv, e0.z, sacc[2]);  sacc[3]  = fmaf(xv, e0.w, sacc[3]);
        sacc[4]  = fmaf(xv, e1.x, sacc[4]);  sacc[5]  = fmaf(xv, e1.y, sacc[5]);
        sacc[6]  = fmaf(xv, e1.z, sacc[6]);  sacc[7]  = fmaf(xv, e1.w, sacc[7]);
        sacc[8]  = fmaf(xv, e2.x, sacc[8]);  sacc[9]  = fmaf(xv, e2.y, sacc[9]);
        sacc[10] = fmaf(xv, e2.z, sacc[10]); sacc[11] = fmaf(xv, e2.w, sacc[11]);
        sacc[12] = fmaf(xv, e3.x, sacc[12]); sacc[13] = fmaf(xv, e3.y, sacc[13]);
        sacc[14] = fmaf(xv, e3.z, sacc[14]); sacc[15] = fmaf(xv, e3.w, sacc[15]);
    }
    unsigned long long best = ~0ull;
    #pragma unroll
    for (int c = 0; c < 16; ++c) {
        int k = j * 16 + c;
        float dd = fmaf(-2.0f, sacc[c], A) + CnL[k];
        unsigned long long pk = (((unsigned long long)__float_as_uint(dd)) << 32) | (unsigned)k;
        best = pk < best ? pk : best;
    }
    #pragma unroll
    for (int s = 1; s < 32; s <<= 1) {
        unsigned long long o = __shfl_xor(best, s, 64);
        best = o < best ? o : best;
    }
    return (int)(best & 0xffffffffu);
}

// ---------------- main: block = 256 thr = 4 waves = 2 row-groups x 2 k-halves.
// Each wave: 32 rows x 256 codes. Merge halves via LDS; exact fallback on ties.
__global__ __launch_bounds__(256) void vq_main(const float* __restrict__ x,
                                               const float* __restrict__ cb,
                                               const float* __restrict__ Cn,
                                               const char* __restrict__ gB,
                                               const float* __restrict__ cbTg,
                                               float* __restrict__ out,
                                               unsigned int* __restrict__ counts,
                                               float* __restrict__ lossSum)
{
    __shared__ float CnL[NUM_K];
    __shared__ float mg_d1[2][2][32], mg_d2[2][2][32];
    __shared__ int   mg_k1[2][2][32];
    __shared__ unsigned short ksL[64];

    const int tid  = threadIdx.x;
    const int lane = tid & 63;
    const int w    = tid >> 6;          // wave 0..3
    const int rg   = w >> 1;            // row-group 0,1
    const int kh   = w & 1;             // codebook half 0,1
    const int half = lane >> 5;
    const int l31  = lane & 31;
    const int bRow0   = blockIdx.x * 64;
    const int rowBase = bRow0 + rg * 32;

    // stage Cn into LDS (2 loads/thread)
    CnL[tid]       = Cn[tid];
    CnL[256 + tid] = Cn[256 + tid];

    // A-frags: this lane's row, bf16 RNE split in regs (verified math)
    short8 ah[4], al[4];
    {
        const float* xr = x + (size_t)(rowBase + l31) * DIM;
        #pragma unroll
        for (int ks = 0; ks < 4; ++ks) {
            int d0 = ks * 16 + half * 8;
            float4 f0 = *(const float4*)(xr + d0);
            float4 f1 = *(const float4*)(xr + d0 + 4);
            float fv[8] = { f0.x, f0.y, f0.z, f0.w, f1.x, f1.y, f1.z, f1.w };
            #pragma unroll
            for (int j = 0; j < 8; ++j) {
                unsigned short hh = f2bf(fv[j]);
                unsigned short ll = f2bf(fv[j] - bf2f(hh));
                ah[ks][j] = (short)hh;
                al[ks][j] = (short)ll;
            }
        }
    }
    __syncthreads();   // CnL ready

    // P1: sweep this wave's 256-code half (8 col-tiles of 32)
    float d1[16], d2[16]; int k1[16];
    #pragma unroll
    for (int r = 0; r < 16; ++r) { d1[r] = 3.4e38f; d2[r] = 3.4e38f; k1[r] = 0; }

    #pragma unroll 1
    for (int ct = 0; ct < 8; ++ct) {
        const int col = kh * 256 + ct * 32 + l31;
        f32x16 acc = (f32x16)0.0f;
        const char* bbase = gB + (size_t)col * 16;
        #pragma unroll
        for (int ks = 0; ks < 4; ++ks) {
            short8 bh = *(const short8*)(bbase + (size_t)(ks * 2 + half) * 8192);
            short8 bl = *(const short8*)(bbase + (size_t)(8 + ks * 2 + half) * 8192);
            acc = __builtin_amdgcn_mfma_f32_32x32x16_bf16(ah[ks], bh, acc, 0, 0, 0);
            acc = __builtin_amdgcn_mfma_f32_32x32x16_bf16(ah[ks], bl, acc, 0, 0, 0);
            acc = __builtin_amdgcn_mfma_f32_32x32x16_bf16(al[ks], bh, acc, 0, 0, 0);
            acc = __builtin_amdgcn_mfma_f32_32x32x16_bf16(al[ks], bl, acc, 0, 0, 0);
        }
        float cv = CnL[col];
        #pragma unroll
        for (int r = 0; r < 16; ++r) {
            float d = fmaf(-2.0f, acc[r], cv);   // rank on C - 2S
            bool c = d < d1[r];
            d2[r] = c ? d1[r] : fminf(d, d2[r]);
            k1[r] = c ? col : k1[r];
            d1[r] = c ? d : d1[r];
        }
    }
    // reduce across the 32 lanes of each half (verified merge)
    #pragma unroll
    for (int r = 0; r < 16; ++r) {
        #pragma unroll
        for (int s = 1; s < 32; s <<= 1) {
            float o1 = __shfl_xor(d1[r], s, 64);
            int   ok = __shfl_xor(k1[r], s, 64);
            float o2 = __shfl_xor(d2[r], s, 64);
            float n1 = fminf(d1[r], o1);
            float n2 = fminf(fmaxf(d1[r], o1), fminf(d2[r], o2));
            int   nk = (o1 < d1[r]) ? ok : ((d1[r] < o1) ? k1[r] : min(k1[r], ok));
            d1[r] = n1; d2[r] = n2; k1[r] = nk;
        }
    }
    // publish this wave's half-result
    if (l31 == 0) {
        #pragma unroll
        for (int r = 0; r < 16; ++r) {
            int rl = (r & 3) + 8 * (r >> 2) + 4 * half;   // verified C-layout
            mg_d1[rg][kh][rl] = d1[r];
            mg_d2[rg][kh][rl] = d2[r];
            mg_k1[rg][kh][rl] = k1[r];
        }
    }
    __syncthreads();

    // kh==0 waves merge halves; exact fallback on uncertifiable gaps
    if (kh == 0) {
        #pragma unroll 1
        for (int r = 0; r < 16; ++r) {
            int rl = (r & 3) + 8 * (r >> 2) + 4 * half;
            float d1a = mg_d1[rg][0][rl], d1b = mg_d1[rg][1][rl];
            float d2a = mg_d2[rg][0][rl], d2b = mg_d2[rg][1][rl];
            int   ka  = mg_k1[rg][0][rl], kb  = mg_k1[rg][1][rl];
            float d1m = fminf(d1a, d1b);
            float d2m = fminf(fmaxf(d1a, d1b), fminf(d2a, d2b));
            int   km  = (d1a < d1b) ? ka : ((d1b < d1a) ? kb : min(ka, kb));
            if (d2m - d1m <= EPS) {
                km = halfScan(x, cb, CnL, rowBase + rl, l31);
            }
            if (l31 == 0) ksL[rg * 32 + rl] = (unsigned short)km;
        }
    }
    __syncthreads();

    // epilogue: wave w -> rows w*16..w*16+15; fully coalesced
    {
        float lacc = 0.0f;
        #pragma unroll 4
        for (int i = 0; i < 16; ++i) {
            int r2  = w * 16 + i;
            int row = bRow0 + r2;
            int kst = ksL[r2];
            float q  = cbTg[(size_t)kst * DIM + lane];
            float xv = x[(size_t)row * DIM + lane];
            float dlt = q - xv;
            out[(size_t)row * DIM + lane] = xv + dlt;      // x + (q - x)
            lacc = fmaf(dlt, dlt, lacc);
            if (lane == 0) atomicAdd(&counts[kst], 1u);
        }
        #pragma unroll
        for (int s = 1; s < 64; s <<= 1) lacc += __shfl_xor(lacc, s, 64);
        if (lane == 0) atomicAdd(lossSum, lacc);
    }
}

__global__ __launch_bounds__(512) void vq_final(const unsigned int* __restrict__ counts,
                                                const float* __restrict__ lossSum,
                                                float* __restrict__ out)
{
    __shared__ float wsum[8];
    int t = threadIdx.x;
    float p = (float)counts[t] * (1.0f / 65536.0f);
    float term = p * logf(p + 1e-10f);
    #pragma unroll
    for (int s = 1; s < 64; s <<= 1) term += __shfl_xor(term, s, 64);
    if ((t & 63) == 0) wsum[t >> 6] = term;
    __syncthreads();
    if (t == 0) {
        float s = 0.0f;
        #pragma unroll
        for (int w = 0; w < 8; ++w) s += wsum[w];
        out[NELEM] = expf(-s);
        float m = (*lossSum) * (1.0f / (float)NELEM);
        out[NELEM + 1] = m;
        out[NELEM + 2] = 0.25f * m;
    }
}

extern "C" void kernel_launch(void* const* d_in, const int* in_sizes, int n_in,
                              void* d_out, int out_size, void* d_ws, size_t ws_size,
                              hipStream_t stream)
{
    const float* x  = (const float*)d_in[0];
    const float* cb = (const float*)d_in[1];
    float* out = (float*)d_out;

    unsigned int* counts = (unsigned int*)d_ws;
    float* lossSum = (float*)((char*)d_ws + 2048);
    float* Cn      = (float*)((char*)d_ws + 4096);
    char*  gB      = (char*)d_ws + 8192;             // 128 KB
    float* cbTg    = (float*)((char*)d_ws + 139264); // 128 KB

    hipMemsetAsync(d_ws, 0, 2052, stream);           // counts + lossSum
    vq_prep <<<4,    128, 0, stream>>>(cb, Cn, gB, cbTg);
    vq_main <<<1024, 256, 0, stream>>>(x, cb, Cn, gB, cbTg, out, counts, lossSum);
    vq_final<<<1,    512, 0, stream>>>(counts, lossSum, out);
}